// Round 7
// baseline (89.034 us; speedup 1.0000x reference)
//
#include <hip/hip_runtime.h>
#include <hip/hip_bf16.h>

typedef __bf16 bf16_t;
typedef __bf16 bf16x8 __attribute__((ext_vector_type(8)));
typedef __bf16 bf16x4 __attribute__((ext_vector_type(4)));
typedef float  f32x4  __attribute__((ext_vector_type(4)));

#define B_   2
#define S_   2048
#define D_   1024
#define H_   16
#define HD_  64
#define HW   32
#define SCALE_ 0.125f
#define NT_  32      // K-tiles of 32
#define BPAD 136     // bounce row pad (elems)

__device__ __forceinline__ void gl_lds16(const bf16_t* g, bf16_t* l) {
  __builtin_amdgcn_global_load_lds(
      (const __attribute__((address_space(1))) void*)g,
      (__attribute__((address_space(3))) void*)l, 16, 0, 0);
}

// ------------- fused converts: x fp32->bf16 (blocks 0..2047), W transpose (2048..3071)
__global__ __launch_bounds__(256) void k_conv(const float* __restrict__ X,
                                              const float* __restrict__ W0,
                                              const float* __restrict__ W1,
                                              const float* __restrict__ W2,
                                              const float* __restrict__ W3,
                                              bf16_t* __restrict__ Xb,
                                              bf16_t* __restrict__ Wt) {
  __shared__ bf16_t t[64][72];
  int bid = blockIdx.x;
  int tid = threadIdx.x;
  if (bid < 2048) {
    int i = bid * 256 + tid;
    const float4 a = ((const float4*)X)[i * 2];
    const float4 b = ((const float4*)X)[i * 2 + 1];
    bf16x8 r;
    r[0] = (bf16_t)a.x; r[1] = (bf16_t)a.y; r[2] = (bf16_t)a.z; r[3] = (bf16_t)a.w;
    r[4] = (bf16_t)b.x; r[5] = (bf16_t)b.y; r[6] = (bf16_t)b.z; r[7] = (bf16_t)b.w;
    ((bf16x8*)Xb)[i] = r;
    return;
  }
  int wb = bid - 2048;
  int wsel = wb >> 8;
  const float* W = (wsel == 0) ? W0 : (wsel == 1) ? W1 : (wsel == 2) ? W2 : W3;
  bf16_t* dst = Wt + (size_t)wsel * D_ * D_;
  int tile = wb & 255;
  int k0 = (tile >> 4) * 64, n0 = (tile & 15) * 64;
  int r = tid >> 4, c4 = (tid & 15) * 4;
#pragma unroll
  for (int i = 0; i < 4; ++i) {
    int row = i * 16 + r;
    float4 v = *(const float4*)(W + (size_t)(k0 + row) * D_ + n0 + c4);
    t[row][c4 + 0] = (bf16_t)v.x;
    t[row][c4 + 1] = (bf16_t)v.y;
    t[row][c4 + 2] = (bf16_t)v.z;
    t[row][c4 + 3] = (bf16_t)v.w;
  }
  __syncthreads();
#pragma unroll
  for (int i = 0; i < 4; ++i) {
    int row = i * 16 + r;
    bf16x4 o;
    o[0] = t[c4 + 0][row];
    o[1] = t[c4 + 1][row];
    o[2] = t[c4 + 2][row];
    o[3] = t[c4 + 3][row];
    *(bf16x4*)(dst + (size_t)(n0 + row) * D_ + k0 + c4) = o;
  }
}

// ---------------- QKV GEMM: 128x128, BK=32, dbuf single-barrier, bounce epilogue ----
__global__ __launch_bounds__(256) void k_gemm_qkv(const bf16_t* __restrict__ X,
                                                  const bf16_t* __restrict__ Wt,
                                                  bf16_t* __restrict__ Q,
                                                  bf16_t* __restrict__ K,
                                                  bf16_t* __restrict__ V) {
  __shared__ bf16_t smem[4][128 * 32];  // [0..1]=A dbuf, [2..3]=B dbuf (32 KB)
  int bid = blockIdx.x;
  int mt = bid & 31, nt = bid >> 5;
  int wsel = nt >> 3;
  int n0 = (nt & 7) * 128, m0 = mt * 128;
  const bf16_t* Wp = Wt + (size_t)wsel * D_ * D_;
  int tid = threadIdx.x, lane = tid & 63, wave = tid >> 6;
  int wr = (wave >> 1) * 64, wc = (wave & 1) * 64;
  int r0 = wave * 32 + (lane >> 2);
  int ce = (lane & 3) * 8;
  const bf16_t* gA0 = X + (size_t)(m0 + r0) * D_ + ce;
  const bf16_t* gB0 = Wp + (size_t)(n0 + r0) * D_ + ce;
  int lofs = wave * 1024;
  f32x4 acc[4][4] = {};
  int kq = (lane >> 4) * 8, rl = lane & 15, hi = lane >> 4;
  // prologue: stage tile 0 into buf 0
  gl_lds16(gA0, &smem[0][lofs]);
  gl_lds16(gA0 + (size_t)16 * D_, &smem[0][lofs + 512]);
  gl_lds16(gB0, &smem[2][lofs]);
  gl_lds16(gB0 + (size_t)16 * D_, &smem[2][lofs + 512]);
  __syncthreads();
  int cur = 0;
  for (int t = 0; t < NT_; ++t) {
    if (t + 1 < NT_) {                      // issue next tile first (overlaps MFMA)
      int kt = (t + 1) * 32, nb = cur ^ 1;
      gl_lds16(gA0 + kt, &smem[nb][lofs]);
      gl_lds16(gA0 + kt + (size_t)16 * D_, &smem[nb][lofs + 512]);
      gl_lds16(gB0 + kt, &smem[2 + nb][lofs]);
      gl_lds16(gB0 + kt + (size_t)16 * D_, &smem[2 + nb][lofs + 512]);
    }
    bf16x8 af[4], bfr[4];
#pragma unroll
    for (int m = 0; m < 4; ++m)
      af[m] = *(const bf16x8*)&smem[cur][(wr + m * 16 + rl) * 32 + kq];
#pragma unroll
    for (int n = 0; n < 4; ++n)
      bfr[n] = *(const bf16x8*)&smem[2 + cur][(wc + n * 16 + rl) * 32 + kq];
#pragma unroll
    for (int m = 0; m < 4; ++m)
#pragma unroll
      for (int n = 0; n < 4; ++n)
        acc[m][n] = __builtin_amdgcn_mfma_f32_16x16x32_bf16(af[m], bfr[n], acc[m][n], 0, 0, 0);
    __syncthreads();   // drains vmcnt(0): next tile landed; all reads of cur done
    cur ^= 1;
  }
  // -------- epilogue: LDS bounce -> bf16x8 coalesced stores --------
  bf16_t* bounce = &smem[0][0];  // 32 KB free now
  if (wsel < 2) {
    bf16_t* Dst = wsel ? K : Q;
    float qs = wsel ? 1.0f : SCALE_;
#pragma unroll
    for (int hh = 0; hh < 2; ++hh) {   // halves along gm (rows)
      if (hh) __syncthreads();
      if ((wr >> 6) == hh) {
#pragma unroll
        for (int m = 0; m < 4; ++m)
#pragma unroll
          for (int n = 0; n < 4; ++n)
#pragma unroll
            for (int r = 0; r < 4; ++r)
              bounce[(m * 16 + hi * 4 + r) * BPAD + wc + n * 16 + rl] =
                  (bf16_t)(acc[m][n][r] * qs);
      }
      __syncthreads();
#pragma unroll
      for (int ps = 0; ps < 4; ++ps) {
        int idx = ps * 256 + tid;
        int row = idx >> 4, c8 = (idx & 15) * 8;
        bf16x8 v = *(const bf16x8*)&bounce[row * BPAD + c8];
        int gm = m0 + hh * 64 + row, gn = n0 + c8;
        int b = gm >> 11, s = gm & 2047, h = gn >> 6, hd = gn & 63;
        *(bf16x8*)&Dst[(((size_t)(b * H_ + h)) * S_ + s) * HD_ + hd] = v;
      }
    }
  } else {
#pragma unroll
    for (int hh = 0; hh < 2; ++hh) {   // halves along gn (hd rows of Vt)
      if (hh) __syncthreads();
      if ((wc >> 6) == hh) {
#pragma unroll
        for (int m = 0; m < 4; ++m)
#pragma unroll
          for (int n = 0; n < 4; ++n)
#pragma unroll
            for (int r = 0; r < 4; ++r)
              bounce[(n * 16 + rl) * BPAD + wr + m * 16 + hi * 4 + r] =
                  (bf16_t)acc[m][n][r];
      }
      __syncthreads();
#pragma unroll
      for (int ps = 0; ps < 4; ++ps) {
        int idx = ps * 256 + tid;
        int row = idx >> 4, c8 = (idx & 15) * 8;
        bf16x8 v = *(const bf16x8*)&bounce[row * BPAD + c8];
        int gn = n0 + hh * 64 + row, gmS = m0 + c8;
        int b = gmS >> 11, s0 = gmS & 2047, h = gn >> 6, hd = gn & 63;
        *(bf16x8*)&V[(((size_t)(b * H_ + h)) * HD_ + hd) * S_ + s0] = v;
      }
    }
  }
}

// ---------------- out GEMM: 128x128, BK=32, dbuf single-barrier ----
__global__ __launch_bounds__(256) void k_gemm_out(const bf16_t* __restrict__ A,
                                                  const bf16_t* __restrict__ Wp,
                                                  const float* __restrict__ bo,
                                                  float* __restrict__ out) {
  __shared__ bf16_t smem[4][128 * 32];
  int bid = blockIdx.x;
  int mt = bid & 31, nt = bid >> 5;
  int n0 = nt * 128, m0 = mt * 128;
  int tid = threadIdx.x, lane = tid & 63, wave = tid >> 6;
  int wr = (wave >> 1) * 64, wc = (wave & 1) * 64;
  int r0 = wave * 32 + (lane >> 2);
  int ce = (lane & 3) * 8;
  const bf16_t* gA0 = A + (size_t)(m0 + r0) * D_ + ce;
  const bf16_t* gB0 = Wp + (size_t)(n0 + r0) * D_ + ce;
  int lofs = wave * 1024;
  f32x4 acc[4][4] = {};
  int kq = (lane >> 4) * 8, rl = lane & 15;
  gl_lds16(gA0, &smem[0][lofs]);
  gl_lds16(gA0 + (size_t)16 * D_, &smem[0][lofs + 512]);
  gl_lds16(gB0, &smem[2][lofs]);
  gl_lds16(gB0 + (size_t)16 * D_, &smem[2][lofs + 512]);
  __syncthreads();
  int cur = 0;
  for (int t = 0; t < NT_; ++t) {
    if (t + 1 < NT_) {
      int kt = (t + 1) * 32, nb = cur ^ 1;
      gl_lds16(gA0 + kt, &smem[nb][lofs]);
      gl_lds16(gA0 + kt + (size_t)16 * D_, &smem[nb][lofs + 512]);
      gl_lds16(gB0 + kt, &smem[2 + nb][lofs]);
      gl_lds16(gB0 + kt + (size_t)16 * D_, &smem[2 + nb][lofs + 512]);
    }
    bf16x8 af[4], bfr[4];
#pragma unroll
    for (int m = 0; m < 4; ++m)
      af[m] = *(const bf16x8*)&smem[cur][(wr + m * 16 + rl) * 32 + kq];
#pragma unroll
    for (int n = 0; n < 4; ++n)
      bfr[n] = *(const bf16x8*)&smem[2 + cur][(wc + n * 16 + rl) * 32 + kq];
#pragma unroll
    for (int m = 0; m < 4; ++m)
#pragma unroll
      for (int n = 0; n < 4; ++n)
        acc[m][n] = __builtin_amdgcn_mfma_f32_16x16x32_bf16(af[m], bfr[n], acc[m][n], 0, 0, 0);
    __syncthreads();
    cur ^= 1;
  }
#pragma unroll
  for (int m = 0; m < 4; ++m) {
#pragma unroll
    for (int n = 0; n < 4; ++n) {
#pragma unroll
      for (int r = 0; r < 4; ++r) {
        int gm = m0 + wr + m * 16 + (lane >> 4) * 4 + r;
        int gn = n0 + wc + n * 16 + rl;
        out[(size_t)gm * D_ + gn] = acc[m][n][r] + bo[gn];
      }
    }
  }
}

// ---------------- MFMA local causal attention (unchanged) ----------------
#define QB 64
#define KW 112
#define KLP 72
#define VTP 120

__global__ __launch_bounds__(256) void k_attn(const bf16_t* __restrict__ Q,
                                              const bf16_t* __restrict__ K,
                                              const bf16_t* __restrict__ Vt,
                                              bf16_t* __restrict__ O) {
  __shared__ bf16_t sK[KW][KLP];
  __shared__ bf16_t sV[HD_][VTP];
  __shared__ bf16_t sQ[QB][KLP];
  __shared__ bf16_t sP[4][16][KLP];
  int bid = blockIdx.x;
  int qb = bid & 31, bh = bid >> 5;
  int q0 = qb * QB;
  const bf16_t* Kp = K + (size_t)bh * S_ * HD_;
  const bf16_t* Vp = Vt + (size_t)bh * HD_ * S_;
  const bf16_t* Qp = Q + (size_t)bh * S_ * HD_;
  int tid = threadIdx.x;
  int wk0b = q0 - HW;
  for (int idx = tid; idx < KW * 8; idx += 256) {
    int row = idx >> 3, c8 = (idx & 7) * 8;
    int kg = wk0b + row;
    kg = kg < 0 ? 0 : (kg > S_ - 1 ? S_ - 1 : kg);
    *(bf16x8*)&sK[row][c8] = *(const bf16x8*)(Kp + (size_t)kg * HD_ + c8);
  }
  for (int idx = tid; idx < HD_ * 14; idx += 256) {
    int row = idx / 14, c8 = (idx % 14) * 8;
    int ks = wk0b + c8;
    ks = ks < 0 ? 0 : (ks > S_ - 8 ? S_ - 8 : ks);
    *(bf16x8*)&sV[row][c8] = *(const bf16x8*)(Vp + (size_t)row * S_ + ks);
  }
  for (int idx = tid; idx < QB * 8; idx += 256) {
    int row = idx >> 3, c8 = (idx & 7) * 8;
    *(bf16x8*)&sQ[row][c8] = *(const bf16x8*)(Qp + (size_t)(q0 + row) * HD_ + c8);
  }
  __syncthreads();
  int lane = tid & 63, wave = tid >> 6;
  int rl = lane & 15, hi = lane >> 4;
  int wko = wave * 16;
  f32x4 accs[4] = {};
#pragma unroll
  for (int ds = 0; ds < 2; ++ds) {
    bf16x8 qf = *(const bf16x8*)&sQ[wave * 16 + rl][ds * 32 + hi * 8];
#pragma unroll
    for (int kb = 0; kb < 4; ++kb) {
      bf16x8 kf = *(const bf16x8*)&sK[wko + kb * 16 + rl][ds * 32 + hi * 8];
      accs[kb] = __builtin_amdgcn_mfma_f32_16x16x32_bf16(kf, qf, accs[kb], 0, 0, 0);
    }
  }
  float p[4][4];
  float mx = -1e30f;
#pragma unroll
  for (int kb = 0; kb < 4; ++kb) {
#pragma unroll
    for (int r = 0; r < 4; ++r) {
      int kl = kb * 16 + hi * 4 + r;
      bool valid = (kl >= rl) && (kl <= rl + HW) && (wk0b + wko + kl >= 0);
      float s = valid ? accs[kb][r] : -1e30f;
      p[kb][r] = s;
      mx = fmaxf(mx, s);
    }
  }
  mx = fmaxf(mx, __shfl_xor(mx, 16));
  mx = fmaxf(mx, __shfl_xor(mx, 32));
  float sum = 0.f;
#pragma unroll
  for (int kb = 0; kb < 4; ++kb)
#pragma unroll
    for (int r = 0; r < 4; ++r) {
      p[kb][r] = __expf(p[kb][r] - mx);
      sum += p[kb][r];
    }
  sum += __shfl_xor(sum, 16);
  sum += __shfl_xor(sum, 32);
  float inv = 1.f / sum;
#pragma unroll
  for (int kb = 0; kb < 4; ++kb) {
    bf16x4 pv;
#pragma unroll
    for (int r = 0; r < 4; ++r) pv[r] = (bf16_t)(p[kb][r] * inv);
    *(bf16x4*)&sP[wave][rl][kb * 16 + hi * 4] = pv;
  }
  f32x4 acco[4] = {};
#pragma unroll
  for (int ks = 0; ks < 2; ++ks) {
    bf16x8 aP = *(const bf16x8*)&sP[wave][rl][ks * 32 + hi * 8];
#pragma unroll
    for (int n = 0; n < 4; ++n) {
      bf16x8 bV = *(const bf16x8*)&sV[n * 16 + rl][wko + ks * 32 + hi * 8];
      acco[n] = __builtin_amdgcn_mfma_f32_16x16x32_bf16(aP, bV, acco[n], 0, 0, 0);
    }
  }
  int b = bh >> 4, h = bh & 15;
#pragma unroll
  for (int n = 0; n < 4; ++n) {
#pragma unroll
    for (int r = 0; r < 4; ++r) {
      int qgl = q0 + wave * 16 + hi * 4 + r;
      int d = n * 16 + rl;
      O[((size_t)(b * S_ + qgl)) * D_ + h * HD_ + d] = (bf16_t)acco[n][r];
    }
  }
}

extern "C" void kernel_launch(void* const* d_in, const int* in_sizes, int n_in,
                              void* d_out, int out_size, void* d_ws, size_t ws_size,
                              hipStream_t stream) {
  const float* x  = (const float*)d_in[0];
  const float* Wq = (const float*)d_in[1];
  const float* Wk = (const float*)d_in[2];
  const float* Wv = (const float*)d_in[3];
  const float* Wo = (const float*)d_in[4];
  const float* bo = (const float*)d_in[5];
  float* out = (float*)d_out;
  char* ws = (char*)d_ws;
  bf16_t* xb = (bf16_t*)(ws);                       // 8 MB
  bf16_t* wt = (bf16_t*)(ws + (size_t)(8 << 20));   // 8 MB [4][1024][1024]
  bf16_t* qb = (bf16_t*)(ws + (size_t)(16 << 20));  // 8 MB [bh][s][64]
  bf16_t* kb = (bf16_t*)(ws + (size_t)(24 << 20));  // 8 MB [bh][s][64]
  bf16_t* vb = (bf16_t*)(ws + (size_t)(32 << 20));  // 8 MB [bh][64][s] (transposed)
  bf16_t* ob = (bf16_t*)(ws + (size_t)(40 << 20));  // 8 MB [b][s][1024]

  hipLaunchKernelGGL(k_conv, dim3(3072), dim3(256), 0, stream,
                     x, Wq, Wk, Wv, Wo, xb, wt);
  hipLaunchKernelGGL(k_gemm_qkv, dim3(768), dim3(256), 0, stream, xb, wt, qb, kb, vb);
  hipLaunchKernelGGL(k_attn, dim3(1024), dim3(256), 0, stream, qb, kb, vb, ob);
  hipLaunchKernelGGL(k_gemm_out, dim3(256), dim3(256), 0, stream,
                     ob, wt + (size_t)3 * D_ * D_, bo, out);
}

// Round 8
// 88.368 us; speedup vs baseline: 1.0075x; 1.0075x over previous
//
#include <hip/hip_runtime.h>
#include <hip/hip_bf16.h>

typedef __bf16 bf16_t;
typedef __bf16 bf16x8 __attribute__((ext_vector_type(8)));
typedef __bf16 bf16x4 __attribute__((ext_vector_type(4)));
typedef float  f32x4  __attribute__((ext_vector_type(4)));

#define B_   2
#define S_   2048
#define D_   1024
#define H_   16
#define HD_  64
#define HW   32
#define SCALE_ 0.125f
#define NT_  32      // K-tiles of 32

__device__ __forceinline__ void gl_lds16(const bf16_t* g, bf16_t* l) {
  __builtin_amdgcn_global_load_lds(
      (const __attribute__((address_space(1))) void*)g,
      (__attribute__((address_space(3))) void*)l, 16, 0, 0);
}

// ------------- fused converts: x fp32->bf16 (blocks 0..2047), W transpose (2048..3071)
__global__ __launch_bounds__(256) void k_conv(const float* __restrict__ X,
                                              const float* __restrict__ W0,
                                              const float* __restrict__ W1,
                                              const float* __restrict__ W2,
                                              const float* __restrict__ W3,
                                              bf16_t* __restrict__ Xb,
                                              bf16_t* __restrict__ Wt) {
  __shared__ bf16_t t[64][72];
  int bid = blockIdx.x;
  int tid = threadIdx.x;
  if (bid < 2048) {
    int i = bid * 256 + tid;
    const float4 a = ((const float4*)X)[i * 2];
    const float4 b = ((const float4*)X)[i * 2 + 1];
    bf16x8 r;
    r[0] = (bf16_t)a.x; r[1] = (bf16_t)a.y; r[2] = (bf16_t)a.z; r[3] = (bf16_t)a.w;
    r[4] = (bf16_t)b.x; r[5] = (bf16_t)b.y; r[6] = (bf16_t)b.z; r[7] = (bf16_t)b.w;
    ((bf16x8*)Xb)[i] = r;
    return;
  }
  int wb = bid - 2048;
  int wsel = wb >> 8;
  const float* W = (wsel == 0) ? W0 : (wsel == 1) ? W1 : (wsel == 2) ? W2 : W3;
  bf16_t* dst = Wt + (size_t)wsel * D_ * D_;
  int tile = wb & 255;
  int k0 = (tile >> 4) * 64, n0 = (tile & 15) * 64;
  int r = tid >> 4, c4 = (tid & 15) * 4;
#pragma unroll
  for (int i = 0; i < 4; ++i) {
    int row = i * 16 + r;
    float4 v = *(const float4*)(W + (size_t)(k0 + row) * D_ + n0 + c4);
    t[row][c4 + 0] = (bf16_t)v.x;
    t[row][c4 + 1] = (bf16_t)v.y;
    t[row][c4 + 2] = (bf16_t)v.z;
    t[row][c4 + 3] = (bf16_t)v.w;
  }
  __syncthreads();
#pragma unroll
  for (int i = 0; i < 4; ++i) {
    int row = i * 16 + r;
    bf16x4 o;
    o[0] = t[c4 + 0][row];
    o[1] = t[c4 + 1][row];
    o[2] = t[c4 + 2][row];
    o[3] = t[c4 + 3][row];
    *(bf16x4*)(dst + (size_t)(n0 + row) * D_ + k0 + c4) = o;
  }
}

// ---- QKV GEMM: 128x128, BK=32, single-barrier dbuf loop, scalar epilogue ----
__global__ __launch_bounds__(256) void k_gemm_qkv(const bf16_t* __restrict__ X,
                                                  const bf16_t* __restrict__ Wt,
                                                  bf16_t* __restrict__ Q,
                                                  bf16_t* __restrict__ K,
                                                  bf16_t* __restrict__ V) {
  __shared__ bf16_t smem[4][128 * 32];  // [0..1]=A dbuf, [2..3]=B dbuf
  int bid = blockIdx.x;
  int mt = bid & 31, nt = bid >> 5;
  int wsel = nt >> 3;
  int n0 = (nt & 7) * 128, m0 = mt * 128;
  const bf16_t* Wp = Wt + (size_t)wsel * D_ * D_;
  int tid = threadIdx.x, lane = tid & 63, wave = tid >> 6;
  int wr = (wave >> 1) * 64, wc = (wave & 1) * 64;
  int r0 = wave * 32 + (lane >> 2);
  int ce = (lane & 3) * 8;
  const bf16_t* gA0 = X + (size_t)(m0 + r0) * D_ + ce;
  const bf16_t* gB0 = Wp + (size_t)(n0 + r0) * D_ + ce;
  int lofs = wave * 1024;
  f32x4 acc[4][4] = {};
  int kq = (lane >> 4) * 8, rl = lane & 15;
  // prologue: stage tile 0 into buf 0
  gl_lds16(gA0, &smem[0][lofs]);
  gl_lds16(gA0 + (size_t)16 * D_, &smem[0][lofs + 512]);
  gl_lds16(gB0, &smem[2][lofs]);
  gl_lds16(gB0 + (size_t)16 * D_, &smem[2][lofs + 512]);
  for (int t = 0; t < NT_; ++t) {
    __syncthreads();                 // tile t landed (vmcnt0); prior reads drained
    int cur = t & 1;
    if (t + 1 < NT_) {               // stage t+1; latency hides under MFMA below
      int kt = (t + 1) * 32, nb = cur ^ 1;
      gl_lds16(gA0 + kt, &smem[nb][lofs]);
      gl_lds16(gA0 + kt + (size_t)16 * D_, &smem[nb][lofs + 512]);
      gl_lds16(gB0 + kt, &smem[2 + nb][lofs]);
      gl_lds16(gB0 + kt + (size_t)16 * D_, &smem[2 + nb][lofs + 512]);
    }
    bf16x8 af[4], bfr[4];
#pragma unroll
    for (int m = 0; m < 4; ++m)
      af[m] = *(const bf16x8*)&smem[cur][(wr + m * 16 + rl) * 32 + kq];
#pragma unroll
    for (int n = 0; n < 4; ++n)
      bfr[n] = *(const bf16x8*)&smem[2 + cur][(wc + n * 16 + rl) * 32 + kq];
#pragma unroll
    for (int m = 0; m < 4; ++m)
#pragma unroll
      for (int n = 0; n < 4; ++n)
        acc[m][n] = __builtin_amdgcn_mfma_f32_16x16x32_bf16(af[m], bfr[n], acc[m][n], 0, 0, 0);
  }
  float qscale = (wsel == 0) ? SCALE_ : 1.0f;
#pragma unroll
  for (int m = 0; m < 4; ++m) {
#pragma unroll
    for (int n = 0; n < 4; ++n) {
#pragma unroll
      for (int r = 0; r < 4; ++r) {
        int gm = m0 + wr + m * 16 + (lane >> 4) * 4 + r;
        int gn = n0 + wc + n * 16 + rl;
        int b = gm >> 11, s = gm & 2047;
        int h = gn >> 6, hd = gn & 63;
        bf16_t val = (bf16_t)(acc[m][n][r] * qscale);
        if (wsel == 0)
          Q[(((size_t)(b * H_ + h)) * S_ + s) * HD_ + hd] = val;
        else if (wsel == 1)
          K[(((size_t)(b * H_ + h)) * S_ + s) * HD_ + hd] = val;
        else
          V[(((size_t)(b * H_ + h)) * HD_ + hd) * S_ + s] = val;  // transposed
      }
    }
  }
}

// ---- out GEMM: 128x128, BK=32, single-barrier dbuf loop ----
__global__ __launch_bounds__(256) void k_gemm_out(const bf16_t* __restrict__ A,
                                                  const bf16_t* __restrict__ Wp,
                                                  const float* __restrict__ bo,
                                                  float* __restrict__ out) {
  __shared__ bf16_t smem[4][128 * 32];
  int bid = blockIdx.x;
  int mt = bid & 31, nt = bid >> 5;
  int n0 = nt * 128, m0 = mt * 128;
  int tid = threadIdx.x, lane = tid & 63, wave = tid >> 6;
  int wr = (wave >> 1) * 64, wc = (wave & 1) * 64;
  int r0 = wave * 32 + (lane >> 2);
  int ce = (lane & 3) * 8;
  const bf16_t* gA0 = A + (size_t)(m0 + r0) * D_ + ce;
  const bf16_t* gB0 = Wp + (size_t)(n0 + r0) * D_ + ce;
  int lofs = wave * 1024;
  f32x4 acc[4][4] = {};
  int kq = (lane >> 4) * 8, rl = lane & 15;
  gl_lds16(gA0, &smem[0][lofs]);
  gl_lds16(gA0 + (size_t)16 * D_, &smem[0][lofs + 512]);
  gl_lds16(gB0, &smem[2][lofs]);
  gl_lds16(gB0 + (size_t)16 * D_, &smem[2][lofs + 512]);
  for (int t = 0; t < NT_; ++t) {
    __syncthreads();
    int cur = t & 1;
    if (t + 1 < NT_) {
      int kt = (t + 1) * 32, nb = cur ^ 1;
      gl_lds16(gA0 + kt, &smem[nb][lofs]);
      gl_lds16(gA0 + kt + (size_t)16 * D_, &smem[nb][lofs + 512]);
      gl_lds16(gB0 + kt, &smem[2 + nb][lofs]);
      gl_lds16(gB0 + kt + (size_t)16 * D_, &smem[2 + nb][lofs + 512]);
    }
    bf16x8 af[4], bfr[4];
#pragma unroll
    for (int m = 0; m < 4; ++m)
      af[m] = *(const bf16x8*)&smem[cur][(wr + m * 16 + rl) * 32 + kq];
#pragma unroll
    for (int n = 0; n < 4; ++n)
      bfr[n] = *(const bf16x8*)&smem[2 + cur][(wc + n * 16 + rl) * 32 + kq];
#pragma unroll
    for (int m = 0; m < 4; ++m)
#pragma unroll
      for (int n = 0; n < 4; ++n)
        acc[m][n] = __builtin_amdgcn_mfma_f32_16x16x32_bf16(af[m], bfr[n], acc[m][n], 0, 0, 0);
  }
#pragma unroll
  for (int m = 0; m < 4; ++m) {
#pragma unroll
    for (int n = 0; n < 4; ++n) {
#pragma unroll
      for (int r = 0; r < 4; ++r) {
        int gm = m0 + wr + m * 16 + (lane >> 4) * 4 + r;
        int gn = n0 + wc + n * 16 + rl;
        out[(size_t)gm * D_ + gn] = acc[m][n][r] + bo[gn];
      }
    }
  }
}

// ---------------- MFMA local causal attention (unchanged) ----------------
#define QB 64
#define KW 112
#define KLP 72
#define VTP 120

__global__ __launch_bounds__(256) void k_attn(const bf16_t* __restrict__ Q,
                                              const bf16_t* __restrict__ K,
                                              const bf16_t* __restrict__ Vt,
                                              bf16_t* __restrict__ O) {
  __shared__ bf16_t sK[KW][KLP];
  __shared__ bf16_t sV[HD_][VTP];
  __shared__ bf16_t sQ[QB][KLP];
  __shared__ bf16_t sP[4][16][KLP];
  int bid = blockIdx.x;
  int qb = bid & 31, bh = bid >> 5;
  int q0 = qb * QB;
  const bf16_t* Kp = K + (size_t)bh * S_ * HD_;
  const bf16_t* Vp = Vt + (size_t)bh * HD_ * S_;
  const bf16_t* Qp = Q + (size_t)bh * S_ * HD_;
  int tid = threadIdx.x;
  int wk0b = q0 - HW;
  for (int idx = tid; idx < KW * 8; idx += 256) {
    int row = idx >> 3, c8 = (idx & 7) * 8;
    int kg = wk0b + row;
    kg = kg < 0 ? 0 : (kg > S_ - 1 ? S_ - 1 : kg);
    *(bf16x8*)&sK[row][c8] = *(const bf16x8*)(Kp + (size_t)kg * HD_ + c8);
  }
  for (int idx = tid; idx < HD_ * 14; idx += 256) {
    int row = idx / 14, c8 = (idx % 14) * 8;
    int ks = wk0b + c8;
    ks = ks < 0 ? 0 : (ks > S_ - 8 ? S_ - 8 : ks);
    *(bf16x8*)&sV[row][c8] = *(const bf16x8*)(Vp + (size_t)row * S_ + ks);
  }
  for (int idx = tid; idx < QB * 8; idx += 256) {
    int row = idx >> 3, c8 = (idx & 7) * 8;
    *(bf16x8*)&sQ[row][c8] = *(const bf16x8*)(Qp + (size_t)(q0 + row) * HD_ + c8);
  }
  __syncthreads();
  int lane = tid & 63, wave = tid >> 6;
  int rl = lane & 15, hi = lane >> 4;
  int wko = wave * 16;
  f32x4 accs[4] = {};
#pragma unroll
  for (int ds = 0; ds < 2; ++ds) {
    bf16x8 qf = *(const bf16x8*)&sQ[wave * 16 + rl][ds * 32 + hi * 8];
#pragma unroll
    for (int kb = 0; kb < 4; ++kb) {
      bf16x8 kf = *(const bf16x8*)&sK[wko + kb * 16 + rl][ds * 32 + hi * 8];
      accs[kb] = __builtin_amdgcn_mfma_f32_16x16x32_bf16(kf, qf, accs[kb], 0, 0, 0);
    }
  }
  float p[4][4];
  float mx = -1e30f;
#pragma unroll
  for (int kb = 0; kb < 4; ++kb) {
#pragma unroll
    for (int r = 0; r < 4; ++r) {
      int kl = kb * 16 + hi * 4 + r;
      bool valid = (kl >= rl) && (kl <= rl + HW) && (wk0b + wko + kl >= 0);
      float s = valid ? accs[kb][r] : -1e30f;
      p[kb][r] = s;
      mx = fmaxf(mx, s);
    }
  }
  mx = fmaxf(mx, __shfl_xor(mx, 16));
  mx = fmaxf(mx, __shfl_xor(mx, 32));
  float sum = 0.f;
#pragma unroll
  for (int kb = 0; kb < 4; ++kb)
#pragma unroll
    for (int r = 0; r < 4; ++r) {
      p[kb][r] = __expf(p[kb][r] - mx);
      sum += p[kb][r];
    }
  sum += __shfl_xor(sum, 16);
  sum += __shfl_xor(sum, 32);
  float inv = 1.f / sum;
#pragma unroll
  for (int kb = 0; kb < 4; ++kb) {
    bf16x4 pv;
#pragma unroll
    for (int r = 0; r < 4; ++r) pv[r] = (bf16_t)(p[kb][r] * inv);
    *(bf16x4*)&sP[wave][rl][kb * 16 + hi * 4] = pv;
  }
  f32x4 acco[4] = {};
#pragma unroll
  for (int ks = 0; ks < 2; ++ks) {
    bf16x8 aP = *(const bf16x8*)&sP[wave][rl][ks * 32 + hi * 8];
#pragma unroll
    for (int n = 0; n < 4; ++n) {
      bf16x8 bV = *(const bf16x8*)&sV[n * 16 + rl][wko + ks * 32 + hi * 8];
      acco[n] = __builtin_amdgcn_mfma_f32_16x16x32_bf16(aP, bV, acco[n], 0, 0, 0);
    }
  }
  int b = bh >> 4, h = bh & 15;
#pragma unroll
  for (int n = 0; n < 4; ++n) {
#pragma unroll
    for (int r = 0; r < 4; ++r) {
      int qgl = q0 + wave * 16 + hi * 4 + r;
      int d = n * 16 + rl;
      O[((size_t)(b * S_ + qgl)) * D_ + h * HD_ + d] = (bf16_t)acco[n][r];
    }
  }
}

extern "C" void kernel_launch(void* const* d_in, const int* in_sizes, int n_in,
                              void* d_out, int out_size, void* d_ws, size_t ws_size,
                              hipStream_t stream) {
  const float* x  = (const float*)d_in[0];
  const float* Wq = (const float*)d_in[1];
  const float* Wk = (const float*)d_in[2];
  const float* Wv = (const float*)d_in[3];
  const float* Wo = (const float*)d_in[4];
  const float* bo = (const float*)d_in[5];
  float* out = (float*)d_out;
  char* ws = (char*)d_ws;
  bf16_t* xb = (bf16_t*)(ws);                       // 8 MB
  bf16_t* wt = (bf16_t*)(ws + (size_t)(8 << 20));   // 8 MB [4][1024][1024]
  bf16_t* qb = (bf16_t*)(ws + (size_t)(16 << 20));  // 8 MB [bh][s][64]
  bf16_t* kb = (bf16_t*)(ws + (size_t)(24 << 20));  // 8 MB [bh][s][64]
  bf16_t* vb = (bf16_t*)(ws + (size_t)(32 << 20));  // 8 MB [bh][64][s] (transposed)
  bf16_t* ob = (bf16_t*)(ws + (size_t)(40 << 20));  // 8 MB [b][s][1024]

  hipLaunchKernelGGL(k_conv, dim3(3072), dim3(256), 0, stream,
                     x, Wq, Wk, Wv, Wo, xb, wt);
  hipLaunchKernelGGL(k_gemm_qkv, dim3(768), dim3(256), 0, stream, xb, wt, qb, kb, vb);
  hipLaunchKernelGGL(k_attn, dim3(1024), dim3(256), 0, stream, qb, kb, vb, ob);
  hipLaunchKernelGGL(k_gemm_out, dim3(256), dim3(256), 0, stream,
                     ob, wt + (size_t)3 * D_ * D_, bo, out);
}